// Round 12
// baseline (228.690 us; speedup 1.0000x reference)
//
#include <hip/hip_runtime.h>

#define NROWS 8192
#define DIN   64
#define DMID  1024
#define DOUT  64
#define NDOM  4
#define PADROWS 9216
#define MAXT128 68
#define NBLK_CONV 4049   // 1 setup + 3920 transpose + 128 X-cast

typedef _Float16 half8 __attribute__((ext_vector_type(8)));
typedef _Float16 half4v __attribute__((ext_vector_type(4)));
typedef float floatx4 __attribute__((ext_vector_type(4)));
typedef float floatx16 __attribute__((ext_vector_type(16)));

__device__ __forceinline__ void gload16(const void* g, void* l) {
  __builtin_amdgcn_global_load_lds((const __attribute__((address_space(1))) void*)g,
                                   (__attribute__((address_space(3))) void*)l, 16, 0, 0);
}

// ---------------- fused conversion + routing-setup kernel ----------------
// block 0: ballot-based domain counting sort (meta/sortpos/invperm)
// mode 0: [b][R][C] f32 -> [b][C][R] f16 (transpose+cast), 64x64 tiles,
//         float4 global loads, half8 global writes
// mode 2: [b][R][C] f32 -> same-layout f16 (plain cast)
struct TDesc { const float* src; _Float16* dst; int R, C, tpb, batch, ofs, mode; };
struct TPack {
  TDesc d[9];
  const int* domains; int* meta; int* sortpos; int* invperm;
};

__global__ void transpose_cast_multi(TPack p) {
  const int g = blockIdx.x;
  const int t = threadIdx.x;

  if (g == 0) {
    // ---- routing setup: wave-ballot counting (few atomics, no serialization) ----
    __shared__ int cnt[NDOM];
    __shared__ int cur[NDOM];
    const int lane = t & 63;
    if (t < NDOM) cnt[t] = 0;
    __syncthreads();
    for (int i = t; i < NROWS; i += 256) {
      int d = p.domains[i];
#pragma unroll
      for (int dd = 0; dd < NDOM; ++dd) {
        unsigned long long mask = __ballot(d == dd);
        if (lane == 0 && mask) atomicAdd(&cnt[dd], __popcll(mask));
      }
    }
    __syncthreads();
    if (t == 0) {
      int* m2 = p.meta + 512;
      int off = 0, T2 = 0;
      for (int d = 0; d < NDOM; ++d) {
        cur[d] = off;
        int c = cnt[d];
        int nt2 = (c + 127) >> 7;
        for (int k = 0; k < nt2; ++k) {
          m2[8 + T2]   = d;
          m2[80 + T2]  = off + k * 128;
          int rem = c - k * 128;
          m2[160 + T2] = rem > 128 ? 128 : rem;
          ++T2;
        }
        off += ((c + 255) >> 8) * 256;   // 256-aligned domain segments
      }
      m2[0] = T2;
    }
    __syncthreads();
    for (int i = t; i < NROWS; i += 256) {
      int d = p.domains[i];
      unsigned long long lt = (1ULL << lane) - 1;
      int pos = 0;
#pragma unroll
      for (int dd = 0; dd < NDOM; ++dd) {
        unsigned long long mask = __ballot(d == dd);
        if (mask) {
          int first = __ffsll((unsigned long long)mask) - 1;
          int cw = __popcll(mask);
          int bw = 0;
          if (lane == first) bw = atomicAdd(&cur[dd], cw);
          bw = __shfl(bw, first, 64);
          if (d == dd) pos = bw + __popcll(mask & lt);
        }
      }
      p.sortpos[i] = pos;
      p.invperm[pos] = i;
    }
    return;
  }

  int i = 0;
#pragma unroll
  for (int j = 1; j < 9; ++j)
    if (g >= p.d[j].ofs) i = j;
  const TDesc D = p.d[i];
  const int local = g - D.ofs;
  const int b  = local / D.tpb;
  const int tx = local - b * D.tpb;
  const int cpr = D.C >> 6;
  const int c0 = (tx % cpr) * 64;
  const int r0 = (tx / cpr) * 64;
  const float* src = D.src + (size_t)b * D.R * D.C;
  _Float16*    dst = D.dst + (size_t)b * D.R * D.C;

  if (D.mode == 2) {
    const int r = r0 + (t >> 2);
    const int cb = c0 + (t & 3) * 16;
    const float* s = src + (size_t)r * D.C + cb;
    _Float16*   d = dst + (size_t)r * D.C + cb;
#pragma unroll
    for (int q = 0; q < 4; ++q) {
      float4 v = *(const float4*)(s + q * 4);
      half4v o;
      o[0] = (_Float16)v.x; o[1] = (_Float16)v.y; o[2] = (_Float16)v.z; o[3] = (_Float16)v.w;
      *(half4v*)(d + q * 4) = o;
    }
    return;
  }

  // mode 0: float4 loads (16B/lane), scalar LDS writes ([64][65] — both phases <=2-way banks)
  __shared__ float tile[64][65];
#pragma unroll
  for (int pp = 0; pp < 4; ++pp) {
    const int r = pp * 16 + (t >> 4);
    const int c4 = (t & 15) * 4;
    float4 v = *(const float4*)(src + (size_t)(r0 + r) * D.C + (c0 + c4));
    tile[r][c4 + 0] = v.x;
    tile[r][c4 + 1] = v.y;
    tile[r][c4 + 2] = v.z;
    tile[r][c4 + 3] = v.w;
  }
  __syncthreads();
#pragma unroll
  for (int pp = 0; pp < 2; ++pp) {
    const int c = (t >> 3) + 32 * pp;
    const int x8 = (t & 7) * 8;
    half8 v;
#pragma unroll
    for (int e = 0; e < 8; ++e) v[e] = (_Float16)tile[x8 + e][c];
    *(half8*)&dst[(size_t)(c0 + c) * D.R + (r0 + x8)] = v;
  }
}

// ---------------- small GEMM (layer 1, K=64) ----------------
template<int BN, int NKT, bool RELU>
__global__ __launch_bounds__(256, 2)
void gemm_f16(const _Float16* __restrict__ A, const _Float16* __restrict__ Bt,
              const float* __restrict__ bias, _Float16* __restrict__ Ch, int ldC) {
  constexpr int BM = 128, BK = 64;
  constexpr int K = NKT * BK;
  constexpr int NFN = BN / 32;
  const int tid = threadIdx.x;
  const int lane = tid & 63, wv = tid >> 6;
  const int lr = lane & 15, lk = lane >> 4;
  const int wr = wv >> 1, wc = wv & 1;

  const int rowbase = blockIdx.y * BM;
  const int n0 = blockIdx.x * BN;

  __shared__ __align__(16) unsigned char sA[BM * BK * 2];
  __shared__ __align__(16) unsigned char sB[BN * BK * 2];

  floatx4 acc[4][NFN];
#pragma unroll
  for (int i = 0; i < 4; ++i)
#pragma unroll
    for (int j = 0; j < NFN; ++j)
      acc[i][j] = (floatx4){0.f, 0.f, 0.f, 0.f};

  const unsigned char* Ab = (const unsigned char*)A + (size_t)rowbase * K * 2;
  const unsigned char* Bb = (const unsigned char*)Bt + (size_t)n0 * K * 2;

  for (int kt = 0; kt < NKT; ++kt) {
    const int kbyte0 = kt * BK * 2;
#pragma unroll
    for (int i = 0; i < 4; ++i) {
      int lo = (wv * 4 + i) * 1024 + lane * 16;
      int row = lo >> 7;
      int kb = lo & 127;
      int gkb = kb ^ ((row & 7) << 4);
      gload16(Ab + (size_t)row * (K * 2) + kbyte0 + gkb, sA + lo);
    }
#pragma unroll
    for (int i = 0; i < BN / 32; ++i) {
      int lo = (wv * (BN / 32) + i) * 1024 + lane * 16;
      int row = lo >> 7;
      int kb = lo & 127;
      int gkb = kb ^ ((row & 7) << 4);
      gload16(Bb + (size_t)row * (K * 2) + kbyte0 + gkb, sB + lo);
    }
    __syncthreads();

#pragma unroll
    for (int kk = 0; kk < 2; ++kk) {
      half8 af[4], bf[NFN];
#pragma unroll
      for (int fm = 0; fm < 4; ++fm) {
        int row = wr * 64 + fm * 16 + lr;
        int kb = kk * 64 + lk * 16;
        int addr = row * 128 + (kb ^ ((row & 7) << 4));
        af[fm] = *(const half8*)(sA + addr);
      }
#pragma unroll
      for (int fn = 0; fn < NFN; ++fn) {
        int row = wc * (BN / 2) + fn * 16 + lr;
        int kb = kk * 64 + lk * 16;
        int addr = row * 128 + (kb ^ ((row & 7) << 4));
        bf[fn] = *(const half8*)(sB + addr);
      }
#pragma unroll
      for (int fm = 0; fm < 4; ++fm)
#pragma unroll
        for (int fn = 0; fn < NFN; ++fn)
          acc[fm][fn] = __builtin_amdgcn_mfma_f32_16x16x32_f16(af[fm], bf[fn], acc[fm][fn], 0, 0, 0);
    }
    __syncthreads();
  }

  const int colbase = n0 + wc * (BN / 2);
#pragma unroll
  for (int fn = 0; fn < NFN; ++fn) {
    const int col = colbase + fn * 16 + lr;
    const float bv = bias[col];
#pragma unroll
    for (int fm = 0; fm < 4; ++fm) {
      const int rl = wr * 64 + fm * 16 + lk * 4;
#pragma unroll
      for (int r = 0; r < 4; ++r) {
        float v = acc[fm][fn][r] + bv;
        if (RELU) v = v > 0.f ? v : 0.f;
        Ch[(size_t)(rowbase + rl + r) * ldC + col] = (_Float16)v;
      }
    }
  }
}

// ---------------- big GEMM (K=1024): R5-exact structure (proven best) ----------------
template<int IN_MODE, int OUT_MODE>
__global__ __launch_bounds__(256, 2)
void gemm_mid(const _Float16* __restrict__ A, const _Float16* __restrict__ Bt,
              const float* __restrict__ bias, _Float16* __restrict__ Ch,
              const int* __restrict__ meta, const int* __restrict__ sortpos,
              int chunk) {
  constexpr int NT = 16;
  __shared__ __align__(16) unsigned char lds[2][32768];

  const int tid = threadIdx.x;
  const int lane = tid & 63, wv = tid >> 6;
  const int lr = lane & 15, lk = lane >> 4;
  const int wr = wv >> 1, wc = wv & 1;

  const int bid = blockIdx.x;
  const int l  = (bid & 7) * chunk + (bid >> 3);
  const int by = l >> 3, bx = l & 7;

  int rowbase;
  const _Float16* Bt2 = Bt;
  const float* bias2 = bias;
  if constexpr (IN_MODE == 1) {
    if (by >= meta[0]) return;
    const int dom = meta[8 + by];
    rowbase = meta[80 + by];
    Bt2   += (size_t)dom * DMID * DMID;
    bias2 += (size_t)dom * DMID;
  } else {
    rowbase = by * 128;
  }
  const int n0 = bx * 128;

  const unsigned char* Ab = (const unsigned char*)A + (size_t)rowbase * 2048;
  const unsigned char* Bb = (const unsigned char*)Bt2 + (size_t)n0 * 2048;

  floatx4 acc[4][4];
#pragma unroll
  for (int i = 0; i < 4; ++i)
#pragma unroll
    for (int j = 0; j < 4; ++j)
      acc[i][j] = (floatx4){0.f, 0.f, 0.f, 0.f};

  int srow[4], soff[4];
#pragma unroll
  for (int i = 0; i < 4; ++i) {
    int lo = i * 4096 + tid * 16;
    srow[i] = lo >> 7;
    int kb = lo & 127;
    soff[i] = kb ^ ((srow[i] & 7) << 4);
  }

  auto stage = [&](int t, int s) {
    const int kb0 = t * 128;
#pragma unroll
    for (int i = 0; i < 4; ++i) {
      int lo = i * 4096 + tid * 16;
      gload16(Ab + (size_t)srow[i] * 2048 + kb0 + soff[i], &lds[s][lo]);
    }
#pragma unroll
    for (int i = 0; i < 4; ++i) {
      int lo = i * 4096 + tid * 16;
      gload16(Bb + (size_t)srow[i] * 2048 + kb0 + soff[i], &lds[s][16384 + lo]);
    }
  };

  int aoff[4][2], boff[4][2];
#pragma unroll
  for (int f = 0; f < 4; ++f) {
    int ra = wr * 64 + f * 16 + lr;
    int rb = wc * 64 + f * 16 + lr;
#pragma unroll
    for (int kk = 0; kk < 2; ++kk) {
      int kb = kk * 64 + lk * 16;
      aoff[f][kk] = ra * 128 + (kb ^ ((ra & 7) << 4));
      boff[f][kk] = 16384 + rb * 128 + (kb ^ ((rb & 7) << 4));
    }
  }

  stage(0, 0);
  asm volatile("s_waitcnt vmcnt(0)" ::: "memory");
  __builtin_amdgcn_s_barrier();
  asm volatile("" ::: "memory");

#pragma unroll
  for (int t = 0; t < NT; ++t) {
    const int s = t & 1;
    if (t + 1 < NT) stage(t + 1, s ^ 1);

    half8 af[4][2], bf[4][2];
#pragma unroll
    for (int f = 0; f < 4; ++f)
#pragma unroll
      for (int kk = 0; kk < 2; ++kk) {
        af[f][kk] = *(const half8*)(&lds[s][aoff[f][kk]]);
        bf[f][kk] = *(const half8*)(&lds[s][boff[f][kk]]);
      }

    __builtin_amdgcn_s_setprio(1);
#pragma unroll
    for (int kk = 0; kk < 2; ++kk)
#pragma unroll
      for (int fm = 0; fm < 4; ++fm)
#pragma unroll
        for (int fn = 0; fn < 4; ++fn)
          acc[fm][fn] = __builtin_amdgcn_mfma_f32_16x16x32_f16(af[fm][kk], bf[fn][kk], acc[fm][fn], 0, 0, 0);
    __builtin_amdgcn_s_setprio(0);

    if (t + 1 < NT) {
      asm volatile("s_waitcnt vmcnt(0)" ::: "memory");
      __builtin_amdgcn_s_barrier();
      asm volatile("" ::: "memory");
    }
  }

  const int colbase = n0 + wc * 64;
#pragma unroll
  for (int fn = 0; fn < 4; ++fn) {
    const int col = colbase + fn * 16 + lr;
    const float bv = bias2[col];
#pragma unroll
    for (int fm = 0; fm < 4; ++fm) {
      const int rl = wr * 64 + fm * 16 + lk * 4;
#pragma unroll
      for (int r = 0; r < 4; ++r) {
        float v = acc[fm][fn][r] + bv;
        v = v > 0.f ? v : 0.f;
        const int row = rowbase + rl + r;
        if constexpr (OUT_MODE == 0) {
          Ch[(size_t)row * DMID + col] = (_Float16)v;
        } else {
          const int orow = sortpos[row];
          Ch[(size_t)orow * DMID + col] = (_Float16)v;
        }
      }
    }
  }
}

// ---------------- final layer: split-K x4 partials + separate reduce ----------------
__global__ __launch_bounds__(256, 2)
void gemm_final(const _Float16* __restrict__ A, const _Float16* __restrict__ Bt,
                const int* __restrict__ meta2, float* __restrict__ P) {
  constexpr int NT = 4;
  __shared__ __align__(16) unsigned char sA[16384];
  __shared__ __align__(16) unsigned char sB[8192];
  const int tid = threadIdx.x;
  const int lane = tid & 63, wv = tid >> 6;
  const int lm = lane & 31, lh = lane >> 5;
  const int bid = blockIdx.x;
  const int ks = bid & 3, t2 = bid >> 2;
  if (t2 >= meta2[0]) return;
  const int dom = meta2[8 + t2];
  const int rowbase = meta2[80 + t2];
  const unsigned char* Ab = (const unsigned char*)A + (size_t)rowbase * 2048 + ks * 512;
  const unsigned char* Bb = (const unsigned char*)Bt + (size_t)dom * DOUT * DMID * 2 + ks * 512;

  floatx16 acc[2];
#pragma unroll
  for (int i = 0; i < 2; ++i)
#pragma unroll
    for (int r = 0; r < 16; ++r)
      acc[i][r] = 0.f;

  for (int t = 0; t < NT; ++t) {
    const int kb0 = t * 128;
#pragma unroll
    for (int i = 0; i < 4; ++i) {
      int lo = i * 4096 + tid * 16;
      int r = lo >> 7, kb = lo & 127;
      gload16(Ab + (size_t)r * 2048 + kb0 + (kb ^ ((r & 7) << 4)), sA + lo);
    }
#pragma unroll
    for (int i = 0; i < 2; ++i) {
      int lo = i * 4096 + tid * 16;
      int r = lo >> 7, kb = lo & 127;
      gload16(Bb + (size_t)r * 2048 + kb0 + (kb ^ ((r & 7) << 4)), sB + lo);
    }
    __syncthreads();

    half8 a2[4], b2[2][4];
#pragma unroll
    for (int j = 0; j < 4; ++j) {
      const int ra = wv * 32 + lm;
      const int kb = j * 32 + lh * 16;
      a2[j] = *(const half8*)(sA + ra * 128 + (kb ^ ((ra & 7) << 4)));
#pragma unroll
      for (int ni = 0; ni < 2; ++ni) {
        const int rb = ni * 32 + lm;
        b2[ni][j] = *(const half8*)(sB + rb * 128 + (kb ^ ((rb & 7) << 4)));
      }
    }
#pragma unroll
    for (int j = 0; j < 4; ++j)
#pragma unroll
      for (int ni = 0; ni < 2; ++ni)
        acc[ni] = __builtin_amdgcn_mfma_f32_32x32x16_f16(a2[j], b2[ni][j], acc[ni], 0, 0, 0);
    __syncthreads();
  }

  float* Pb = P + (size_t)(ks * MAXT128 + t2) * 128 * DOUT;
#pragma unroll
  for (int ni = 0; ni < 2; ++ni) {
    const int col = ni * 32 + lm;
#pragma unroll
    for (int reg = 0; reg < 16; ++reg) {
      const int row = wv * 32 + (reg & 3) + 8 * (reg >> 2) + 4 * lh;
      Pb[(size_t)row * DOUT + col] = acc[ni][reg];
    }
  }
}

__global__ void reduce_final(const float* __restrict__ P, const float* __restrict__ Bb4,
                             const int* __restrict__ meta2, const int* __restrict__ invperm,
                             float* __restrict__ out) {
  const int t2 = blockIdx.x;
  if (t2 >= meta2[0]) return;
  const int dom   = meta2[8 + t2];
  const int base  = meta2[80 + t2];
  const int valid = meta2[160 + t2];
  const int tid = threadIdx.x;
  for (int e = tid; e < 128 * DOUT; e += 256) {
    const int row = e >> 6, col = e & 63;
    if (row < valid) {
      float v = Bb4[dom * DOUT + col];
#pragma unroll
      for (int ks = 0; ks < 4; ++ks)
        v += P[((size_t)(ks * MAXT128 + t2) * 128 + row) * DOUT + col];
      out[(size_t)invperm[base + row] * DOUT + col] = v;
    }
  }
}

// ---------------- launch ----------------

extern "C" void kernel_launch(void* const* d_in, const int* in_sizes, int n_in,
                              void* d_out, int out_size, void* d_ws, size_t ws_size,
                              hipStream_t stream) {
  const float* X   = (const float*)d_in[0];
  const int* domains = (const int*)d_in[1];
  const float* W1  = (const float*)d_in[2];
  const float* b1  = (const float*)d_in[3];
  const float* W2  = (const float*)d_in[4];
  const float* b2  = (const float*)d_in[5];
  const float* W3  = (const float*)d_in[6];
  const float* b3  = (const float*)d_in[7];
  const float* W4  = (const float*)d_in[8];
  const float* b4  = (const float*)d_in[9];
  const float* BW1 = (const float*)d_in[10];
  const float* Bb1 = (const float*)d_in[11];
  const float* BW2 = (const float*)d_in[12];
  const float* Bb2 = (const float*)d_in[13];
  const float* BW3 = (const float*)d_in[14];
  const float* Bb3 = (const float*)d_in[15];
  const float* BW4 = (const float*)d_in[16];
  const float* Bb4 = (const float*)d_in[17];
  float* out = (float*)d_out;

  char* base = (char*)d_ws;
  size_t off = 0;
  auto alloc = [&](size_t bytes) -> void* {
    void* p = base + off;
    off = (off + bytes + 255) & ~(size_t)255;
    return p;
  };
  _Float16* Xh   = (_Float16*)alloc((size_t)NROWS * DIN * 2);
  _Float16* W1t  = (_Float16*)alloc((size_t)DMID * DIN * 2);
  _Float16* W2t  = (_Float16*)alloc((size_t)DMID * DMID * 2);
  _Float16* W3t  = (_Float16*)alloc((size_t)DMID * DMID * 2);
  _Float16* W4t  = (_Float16*)alloc((size_t)DMID * DMID * 2);
  _Float16* BW1t = (_Float16*)alloc((size_t)NDOM * DMID * DMID * 2);
  _Float16* BW2t = (_Float16*)alloc((size_t)NDOM * DMID * DMID * 2);
  _Float16* BW3t = (_Float16*)alloc((size_t)NDOM * DMID * DMID * 2);
  _Float16* BW4t = (_Float16*)alloc((size_t)NDOM * DOUT * DMID * 2);
  _Float16* bufA = (_Float16*)alloc((size_t)NROWS * DMID * 2);
  _Float16* bufS0= (_Float16*)alloc((size_t)PADROWS * DMID * 2);
  _Float16* bufS1= (_Float16*)alloc((size_t)PADROWS * DMID * 2);
  float* Pbuf    = (float*)alloc((size_t)4 * MAXT128 * 128 * DOUT * 4);
  int* sortpos   = (int*)alloc((size_t)NROWS * 4);
  int* invperm   = (int*)alloc((size_t)PADROWS * 4);
  int* meta      = (int*)alloc(1024 * 4);
  int* meta2     = meta + 512;

  // fused: setup (block 0) + 8 weight transposes (mode 0) + X cast (mode 2)
  TPack tp;
  tp.d[0] = {W1,  W1t,  DIN,  DMID, (DIN/64)*(DMID/64),  1,    1, 0};
  tp.d[1] = {W2,  W2t,  DMID, DMID, (DMID/64)*(DMID/64), 1,   17, 0};
  tp.d[2] = {W3,  W3t,  DMID, DMID, (DMID/64)*(DMID/64), 1,  273, 0};
  tp.d[3] = {W4,  W4t,  DMID, DMID, (DMID/64)*(DMID/64), 1,  529, 0};
  tp.d[4] = {BW1, BW1t, DMID, DMID, (DMID/64)*(DMID/64), NDOM, 785, 0};
  tp.d[5] = {BW2, BW2t, DMID, DMID, (DMID/64)*(DMID/64), NDOM, 1809, 0};
  tp.d[6] = {BW3, BW3t, DMID, DMID, (DMID/64)*(DMID/64), NDOM, 2833, 0};
  tp.d[7] = {BW4, BW4t, DMID, DOUT, (DMID/64)*(DOUT/64), NDOM, 3857, 0};
  tp.d[8] = {X,   Xh,   NROWS, DIN, (NROWS/64)*(DIN/64), 1,   3921, 2};
  tp.domains = domains; tp.meta = meta; tp.sortpos = sortpos; tp.invperm = invperm;
  transpose_cast_multi<<<NBLK_CONV, 256, 0, stream>>>(tp);

  // layer 1 (K=64)
  gemm_f16<128, 1, true><<<dim3(DMID / 128, NROWS / 128), 256, 0, stream>>>(
      Xh, W1t, b1, bufA, DMID);

  // big K=1024 layers: dense grid 512 (64 row-tiles x 8 col), chunk 64
  gemm_mid<0, 0><<<512, 256, 0, stream>>>(bufA,  W2t, b2, bufS1, nullptr, nullptr, 64);
  gemm_mid<0, 0><<<512, 256, 0, stream>>>(bufS1, W3t, b3, bufA,  nullptr, nullptr, 64);
  gemm_mid<0, 1><<<512, 256, 0, stream>>>(bufA,  W4t, b4, bufS0, nullptr, sortpos, 64);
  // branch layers: grid 544 (68 x 8), chunk 68, 128-gran tile map
  gemm_mid<1, 0><<<544, 256, 0, stream>>>(bufS0, BW1t, Bb1, bufS1, meta2, nullptr, MAXT128);
  gemm_mid<1, 0><<<544, 256, 0, stream>>>(bufS1, BW2t, Bb2, bufS0, meta2, nullptr, MAXT128);
  gemm_mid<1, 0><<<544, 256, 0, stream>>>(bufS0, BW3t, Bb3, bufS1, meta2, nullptr, MAXT128);

  // final layer: split-K x4 partials, then reduce (+bias, +scatter)
  gemm_final<<<4 * MAXT128, 256, 0, stream>>>(bufS1, BW4t, meta2, Pbuf);
  reduce_final<<<MAXT128, 256, 0, stream>>>(Pbuf, Bb4, meta2, invperm, out);
}

// Round 13
// 202.364 us; speedup vs baseline: 1.1301x; 1.1301x over previous
//
#include <hip/hip_runtime.h>

#define NROWS 8192
#define DIN   64
#define DMID  1024
#define DOUT  64
#define NDOM  4
#define PADROWS 9216
#define MAXT128 68

typedef _Float16 half8 __attribute__((ext_vector_type(8)));
typedef _Float16 half4v __attribute__((ext_vector_type(4)));
typedef float floatx4 __attribute__((ext_vector_type(4)));
typedef float floatx16 __attribute__((ext_vector_type(16)));

__device__ __forceinline__ void gload16(const void* g, void* l) {
  __builtin_amdgcn_global_load_lds((const __attribute__((address_space(1))) void*)g,
                                   (__attribute__((address_space(3))) void*)l, 16, 0, 0);
}

// ---------------- fused conversion kernel (R9 champion form) ----------------
// mode 0: [b][R][C] f32 -> [b][C][R] f16 (transpose+cast), 64x64 tiles,
//         scalar coalesced loads, half8 vectorized writes
// mode 2: [b][R][C] f32 -> same-layout f16 (plain cast)
struct TDesc { const float* src; _Float16* dst; int R, C, tpb, batch, ofs, mode; };
struct TPack { TDesc d[9]; };

__global__ void transpose_cast_multi(TPack p) {
  const int g = blockIdx.x;
  const int t = threadIdx.x;

  int i = 0;
#pragma unroll
  for (int j = 1; j < 9; ++j)
    if (g >= p.d[j].ofs) i = j;
  const TDesc D = p.d[i];
  const int local = g - D.ofs;
  const int b  = local / D.tpb;
  const int tx = local - b * D.tpb;
  const int cpr = D.C >> 6;
  const int c0 = (tx % cpr) * 64;
  const int r0 = (tx / cpr) * 64;
  const float* src = D.src + (size_t)b * D.R * D.C;
  _Float16*    dst = D.dst + (size_t)b * D.R * D.C;

  if (D.mode == 2) {
    const int r = r0 + (t >> 2);
    const int cb = c0 + (t & 3) * 16;
    const float* s = src + (size_t)r * D.C + cb;
    _Float16*   d = dst + (size_t)r * D.C + cb;
#pragma unroll
    for (int q = 0; q < 4; ++q) {
      float4 v = *(const float4*)(s + q * 4);
      half4v o;
      o[0] = (_Float16)v.x; o[1] = (_Float16)v.y; o[2] = (_Float16)v.z; o[3] = (_Float16)v.w;
      *(half4v*)(d + q * 4) = o;
    }
    return;
  }

  __shared__ float tile[64][65];
  const int x = t & 63;
  const int y4 = t >> 6;
#pragma unroll
  for (int k = 0; k < 16; ++k) {
    int r = y4 * 16 + k;
    tile[r][x] = src[(size_t)(r0 + r) * D.C + (c0 + x)];
  }
  __syncthreads();
#pragma unroll
  for (int pp = 0; pp < 2; ++pp) {
    const int c = (t >> 3) + 32 * pp;
    const int x8 = (t & 7) * 8;
    half8 v;
#pragma unroll
    for (int e = 0; e < 8; ++e) v[e] = (_Float16)tile[x8 + e][c];
    *(half8*)&dst[(size_t)(c0 + c) * D.R + (r0 + x8)] = v;
  }
}

// ---------------- routing setup ----------------
// meta+512 (128-gran): [0]=T2, [8+t]=dom, [80+t]=base, [160+t]=valid
__global__ void setup_kernel(const int* __restrict__ domains, int* __restrict__ meta,
                             int* __restrict__ sortpos, int* __restrict__ invperm) {
  __shared__ int cnt[NDOM];
  __shared__ int cur[NDOM];
  const int t = threadIdx.x;
  if (t < NDOM) cnt[t] = 0;
  __syncthreads();
  for (int i = t; i < NROWS; i += blockDim.x)
    atomicAdd(&cnt[domains[i]], 1);
  __syncthreads();
  if (t == 0) {
    int* m2 = meta + 512;
    int off = 0, T2 = 0;
    for (int d = 0; d < NDOM; ++d) {
      cur[d] = off;
      int c = cnt[d];
      int nt2 = (c + 127) >> 7;
      for (int k = 0; k < nt2; ++k) {
        m2[8 + T2]   = d;
        m2[80 + T2]  = off + k * 128;
        int rem = c - k * 128;
        m2[160 + T2] = rem > 128 ? 128 : rem;
        ++T2;
      }
      off += ((c + 255) >> 8) * 256;   // 256-aligned domain segments
    }
    m2[0] = T2;
  }
  __syncthreads();
  for (int i = t; i < NROWS; i += blockDim.x) {
    int d = domains[i];
    int p = atomicAdd(&cur[d], 1);
    sortpos[i] = p;
    invperm[p] = i;
  }
}

// ---------------- small GEMM (layer 1, K=64) ----------------
template<int BN, int NKT, bool RELU>
__global__ __launch_bounds__(256, 2)
void gemm_f16(const _Float16* __restrict__ A, const _Float16* __restrict__ Bt,
              const float* __restrict__ bias, _Float16* __restrict__ Ch, int ldC) {
  constexpr int BM = 128, BK = 64;
  constexpr int K = NKT * BK;
  constexpr int NFN = BN / 32;
  const int tid = threadIdx.x;
  const int lane = tid & 63, wv = tid >> 6;
  const int lr = lane & 15, lk = lane >> 4;
  const int wr = wv >> 1, wc = wv & 1;

  const int rowbase = blockIdx.y * BM;
  const int n0 = blockIdx.x * BN;

  __shared__ __align__(16) unsigned char sA[BM * BK * 2];
  __shared__ __align__(16) unsigned char sB[BN * BK * 2];

  floatx4 acc[4][NFN];
#pragma unroll
  for (int i = 0; i < 4; ++i)
#pragma unroll
    for (int j = 0; j < NFN; ++j)
      acc[i][j] = (floatx4){0.f, 0.f, 0.f, 0.f};

  const unsigned char* Ab = (const unsigned char*)A + (size_t)rowbase * K * 2;
  const unsigned char* Bb = (const unsigned char*)Bt + (size_t)n0 * K * 2;

  for (int kt = 0; kt < NKT; ++kt) {
    const int kbyte0 = kt * BK * 2;
#pragma unroll
    for (int i = 0; i < 4; ++i) {
      int lo = (wv * 4 + i) * 1024 + lane * 16;
      int row = lo >> 7;
      int kb = lo & 127;
      int gkb = kb ^ ((row & 7) << 4);
      gload16(Ab + (size_t)row * (K * 2) + kbyte0 + gkb, sA + lo);
    }
#pragma unroll
    for (int i = 0; i < BN / 32; ++i) {
      int lo = (wv * (BN / 32) + i) * 1024 + lane * 16;
      int row = lo >> 7;
      int kb = lo & 127;
      int gkb = kb ^ ((row & 7) << 4);
      gload16(Bb + (size_t)row * (K * 2) + kbyte0 + gkb, sB + lo);
    }
    __syncthreads();

#pragma unroll
    for (int kk = 0; kk < 2; ++kk) {
      half8 af[4], bf[NFN];
#pragma unroll
      for (int fm = 0; fm < 4; ++fm) {
        int row = wr * 64 + fm * 16 + lr;
        int kb = kk * 64 + lk * 16;
        int addr = row * 128 + (kb ^ ((row & 7) << 4));
        af[fm] = *(const half8*)(sA + addr);
      }
#pragma unroll
      for (int fn = 0; fn < NFN; ++fn) {
        int row = wc * (BN / 2) + fn * 16 + lr;
        int kb = kk * 64 + lk * 16;
        int addr = row * 128 + (kb ^ ((row & 7) << 4));
        bf[fn] = *(const half8*)(sB + addr);
      }
#pragma unroll
      for (int fm = 0; fm < 4; ++fm)
#pragma unroll
        for (int fn = 0; fn < NFN; ++fn)
          acc[fm][fn] = __builtin_amdgcn_mfma_f32_16x16x32_f16(af[fm], bf[fn], acc[fm][fn], 0, 0, 0);
    }
    __syncthreads();
  }

  const int colbase = n0 + wc * (BN / 2);
#pragma unroll
  for (int fn = 0; fn < NFN; ++fn) {
    const int col = colbase + fn * 16 + lr;
    const float bv = bias[col];
#pragma unroll
    for (int fm = 0; fm < 4; ++fm) {
      const int rl = wr * 64 + fm * 16 + lk * 4;
#pragma unroll
      for (int r = 0; r < 4; ++r) {
        float v = acc[fm][fn][r] + bv;
        if (RELU) v = v > 0.f ? v : 0.f;
        Ch[(size_t)(rowbase + rl + r) * ldC + col] = (_Float16)v;
      }
    }
  }
}

// ---------------- big GEMM (K=1024): R5-exact structure (proven best) ----------------
template<int IN_MODE, int OUT_MODE>
__global__ __launch_bounds__(256, 2)
void gemm_mid(const _Float16* __restrict__ A, const _Float16* __restrict__ Bt,
              const float* __restrict__ bias, _Float16* __restrict__ Ch,
              const int* __restrict__ meta, const int* __restrict__ sortpos,
              int chunk) {
  constexpr int NT = 16;
  __shared__ __align__(16) unsigned char lds[2][32768];

  const int tid = threadIdx.x;
  const int lane = tid & 63, wv = tid >> 6;
  const int lr = lane & 15, lk = lane >> 4;
  const int wr = wv >> 1, wc = wv & 1;

  const int bid = blockIdx.x;
  const int l  = (bid & 7) * chunk + (bid >> 3);
  const int by = l >> 3, bx = l & 7;

  int rowbase;
  const _Float16* Bt2 = Bt;
  const float* bias2 = bias;
  if constexpr (IN_MODE == 1) {
    if (by >= meta[0]) return;
    const int dom = meta[8 + by];
    rowbase = meta[80 + by];
    Bt2   += (size_t)dom * DMID * DMID;
    bias2 += (size_t)dom * DMID;
  } else {
    rowbase = by * 128;
  }
  const int n0 = bx * 128;

  const unsigned char* Ab = (const unsigned char*)A + (size_t)rowbase * 2048;
  const unsigned char* Bb = (const unsigned char*)Bt2 + (size_t)n0 * 2048;

  floatx4 acc[4][4];
#pragma unroll
  for (int i = 0; i < 4; ++i)
#pragma unroll
    for (int j = 0; j < 4; ++j)
      acc[i][j] = (floatx4){0.f, 0.f, 0.f, 0.f};

  int srow[4], soff[4];
#pragma unroll
  for (int i = 0; i < 4; ++i) {
    int lo = i * 4096 + tid * 16;
    srow[i] = lo >> 7;
    int kb = lo & 127;
    soff[i] = kb ^ ((srow[i] & 7) << 4);
  }

  auto stage = [&](int t, int s) {
    const int kb0 = t * 128;
#pragma unroll
    for (int i = 0; i < 4; ++i) {
      int lo = i * 4096 + tid * 16;
      gload16(Ab + (size_t)srow[i] * 2048 + kb0 + soff[i], &lds[s][lo]);
    }
#pragma unroll
    for (int i = 0; i < 4; ++i) {
      int lo = i * 4096 + tid * 16;
      gload16(Bb + (size_t)srow[i] * 2048 + kb0 + soff[i], &lds[s][16384 + lo]);
    }
  };

  int aoff[4][2], boff[4][2];
#pragma unroll
  for (int f = 0; f < 4; ++f) {
    int ra = wr * 64 + f * 16 + lr;
    int rb = wc * 64 + f * 16 + lr;
#pragma unroll
    for (int kk = 0; kk < 2; ++kk) {
      int kb = kk * 64 + lk * 16;
      aoff[f][kk] = ra * 128 + (kb ^ ((ra & 7) << 4));
      boff[f][kk] = 16384 + rb * 128 + (kb ^ ((rb & 7) << 4));
    }
  }

  stage(0, 0);
  asm volatile("s_waitcnt vmcnt(0)" ::: "memory");
  __builtin_amdgcn_s_barrier();
  asm volatile("" ::: "memory");

#pragma unroll
  for (int t = 0; t < NT; ++t) {
    const int s = t & 1;
    if (t + 1 < NT) stage(t + 1, s ^ 1);

    half8 af[4][2], bf[4][2];
#pragma unroll
    for (int f = 0; f < 4; ++f)
#pragma unroll
      for (int kk = 0; kk < 2; ++kk) {
        af[f][kk] = *(const half8*)(&lds[s][aoff[f][kk]]);
        bf[f][kk] = *(const half8*)(&lds[s][boff[f][kk]]);
      }

    __builtin_amdgcn_s_setprio(1);
#pragma unroll
    for (int kk = 0; kk < 2; ++kk)
#pragma unroll
      for (int fm = 0; fm < 4; ++fm)
#pragma unroll
        for (int fn = 0; fn < 4; ++fn)
          acc[fm][fn] = __builtin_amdgcn_mfma_f32_16x16x32_f16(af[fm][kk], bf[fn][kk], acc[fm][fn], 0, 0, 0);
    __builtin_amdgcn_s_setprio(0);

    if (t + 1 < NT) {
      asm volatile("s_waitcnt vmcnt(0)" ::: "memory");
      __builtin_amdgcn_s_barrier();
      asm volatile("" ::: "memory");
    }
  }

  const int colbase = n0 + wc * 64;
#pragma unroll
  for (int fn = 0; fn < 4; ++fn) {
    const int col = colbase + fn * 16 + lr;
    const float bv = bias2[col];
#pragma unroll
    for (int fm = 0; fm < 4; ++fm) {
      const int rl = wr * 64 + fm * 16 + lk * 4;
#pragma unroll
      for (int r = 0; r < 4; ++r) {
        float v = acc[fm][fn][r] + bv;
        v = v > 0.f ? v : 0.f;
        const int row = rowbase + rl + r;
        if constexpr (OUT_MODE == 0) {
          Ch[(size_t)row * DMID + col] = (_Float16)v;
        } else {
          const int orow = sortpos[row];
          Ch[(size_t)orow * DMID + col] = (_Float16)v;
        }
      }
    }
  }
}

// ---------------- final layer: split-K x4 partials + separate reduce ----------------
__global__ __launch_bounds__(256, 2)
void gemm_final(const _Float16* __restrict__ A, const _Float16* __restrict__ Bt,
                const int* __restrict__ meta2, float* __restrict__ P) {
  constexpr int NT = 4;
  __shared__ __align__(16) unsigned char sA[16384];
  __shared__ __align__(16) unsigned char sB[8192];
  const int tid = threadIdx.x;
  const int lane = tid & 63, wv = tid >> 6;
  const int lm = lane & 31, lh = lane >> 5;
  const int bid = blockIdx.x;
  const int ks = bid & 3, t2 = bid >> 2;
  if (t2 >= meta2[0]) return;
  const int dom = meta2[8 + t2];
  const int rowbase = meta2[80 + t2];
  const unsigned char* Ab = (const unsigned char*)A + (size_t)rowbase * 2048 + ks * 512;
  const unsigned char* Bb = (const unsigned char*)Bt + (size_t)dom * DOUT * DMID * 2 + ks * 512;

  floatx16 acc[2];
#pragma unroll
  for (int i = 0; i < 2; ++i)
#pragma unroll
    for (int r = 0; r < 16; ++r)
      acc[i][r] = 0.f;

  for (int t = 0; t < NT; ++t) {
    const int kb0 = t * 128;
#pragma unroll
    for (int i = 0; i < 4; ++i) {
      int lo = i * 4096 + tid * 16;
      int r = lo >> 7, kb = lo & 127;
      gload16(Ab + (size_t)r * 2048 + kb0 + (kb ^ ((r & 7) << 4)), sA + lo);
    }
#pragma unroll
    for (int i = 0; i < 2; ++i) {
      int lo = i * 4096 + tid * 16;
      int r = lo >> 7, kb = lo & 127;
      gload16(Bb + (size_t)r * 2048 + kb0 + (kb ^ ((r & 7) << 4)), sB + lo);
    }
    __syncthreads();

    half8 a2[4], b2[2][4];
#pragma unroll
    for (int j = 0; j < 4; ++j) {
      const int ra = wv * 32 + lm;
      const int kb = j * 32 + lh * 16;
      a2[j] = *(const half8*)(sA + ra * 128 + (kb ^ ((ra & 7) << 4)));
#pragma unroll
      for (int ni = 0; ni < 2; ++ni) {
        const int rb = ni * 32 + lm;
        b2[ni][j] = *(const half8*)(sB + rb * 128 + (kb ^ ((rb & 7) << 4)));
      }
    }
#pragma unroll
    for (int j = 0; j < 4; ++j)
#pragma unroll
      for (int ni = 0; ni < 2; ++ni)
        acc[ni] = __builtin_amdgcn_mfma_f32_32x32x16_f16(a2[j], b2[ni][j], acc[ni], 0, 0, 0);
    __syncthreads();
  }

  float* Pb = P + (size_t)(ks * MAXT128 + t2) * 128 * DOUT;
#pragma unroll
  for (int ni = 0; ni < 2; ++ni) {
    const int col = ni * 32 + lm;
#pragma unroll
    for (int reg = 0; reg < 16; ++reg) {
      const int row = wv * 32 + (reg & 3) + 8 * (reg >> 2) + 4 * lh;
      Pb[(size_t)row * DOUT + col] = acc[ni][reg];
    }
  }
}

__global__ void reduce_final(const float* __restrict__ P, const float* __restrict__ Bb4,
                             const int* __restrict__ meta2, const int* __restrict__ invperm,
                             float* __restrict__ out) {
  const int t2 = blockIdx.x;
  if (t2 >= meta2[0]) return;
  const int dom   = meta2[8 + t2];
  const int base  = meta2[80 + t2];
  const int valid = meta2[160 + t2];
  const int tid = threadIdx.x;
  for (int e = tid; e < 128 * DOUT; e += 256) {
    const int row = e >> 6, col = e & 63;
    if (row < valid) {
      float v = Bb4[dom * DOUT + col];
#pragma unroll
      for (int ks = 0; ks < 4; ++ks)
        v += P[((size_t)(ks * MAXT128 + t2) * 128 + row) * DOUT + col];
      out[(size_t)invperm[base + row] * DOUT + col] = v;
    }
  }
}

// ---------------- launch ----------------

extern "C" void kernel_launch(void* const* d_in, const int* in_sizes, int n_in,
                              void* d_out, int out_size, void* d_ws, size_t ws_size,
                              hipStream_t stream) {
  const float* X   = (const float*)d_in[0];
  const int* domains = (const int*)d_in[1];
  const float* W1  = (const float*)d_in[2];
  const float* b1  = (const float*)d_in[3];
  const float* W2  = (const float*)d_in[4];
  const float* b2  = (const float*)d_in[5];
  const float* W3  = (const float*)d_in[6];
  const float* b3  = (const float*)d_in[7];
  const float* W4  = (const float*)d_in[8];
  const float* b4  = (const float*)d_in[9];
  const float* BW1 = (const float*)d_in[10];
  const float* Bb1 = (const float*)d_in[11];
  const float* BW2 = (const float*)d_in[12];
  const float* Bb2 = (const float*)d_in[13];
  const float* BW3 = (const float*)d_in[14];
  const float* Bb3 = (const float*)d_in[15];
  const float* BW4 = (const float*)d_in[16];
  const float* Bb4 = (const float*)d_in[17];
  float* out = (float*)d_out;

  char* base = (char*)d_ws;
  size_t off = 0;
  auto alloc = [&](size_t bytes) -> void* {
    void* p = base + off;
    off = (off + bytes + 255) & ~(size_t)255;
    return p;
  };
  _Float16* Xh   = (_Float16*)alloc((size_t)NROWS * DIN * 2);
  _Float16* W1t  = (_Float16*)alloc((size_t)DMID * DIN * 2);
  _Float16* W2t  = (_Float16*)alloc((size_t)DMID * DMID * 2);
  _Float16* W3t  = (_Float16*)alloc((size_t)DMID * DMID * 2);
  _Float16* W4t  = (_Float16*)alloc((size_t)DMID * DMID * 2);
  _Float16* BW1t = (_Float16*)alloc((size_t)NDOM * DMID * DMID * 2);
  _Float16* BW2t = (_Float16*)alloc((size_t)NDOM * DMID * DMID * 2);
  _Float16* BW3t = (_Float16*)alloc((size_t)NDOM * DMID * DMID * 2);
  _Float16* BW4t = (_Float16*)alloc((size_t)NDOM * DOUT * DMID * 2);
  _Float16* bufA = (_Float16*)alloc((size_t)NROWS * DMID * 2);
  _Float16* bufS0= (_Float16*)alloc((size_t)PADROWS * DMID * 2);
  _Float16* bufS1= (_Float16*)alloc((size_t)PADROWS * DMID * 2);
  float* Pbuf    = (float*)alloc((size_t)4 * MAXT128 * 128 * DOUT * 4);
  int* sortpos   = (int*)alloc((size_t)NROWS * 4);
  int* invperm   = (int*)alloc((size_t)PADROWS * 4);
  int* meta      = (int*)alloc(1024 * 4);
  int* meta2     = meta + 512;

  // fused conversions: 8 weight transposes (mode 0) + X cast (mode 2)
  TPack tp;
  tp.d[0] = {W1,  W1t,  DIN,  DMID, (DIN/64)*(DMID/64),  1,    0, 0};
  tp.d[1] = {W2,  W2t,  DMID, DMID, (DMID/64)*(DMID/64), 1,   16, 0};
  tp.d[2] = {W3,  W3t,  DMID, DMID, (DMID/64)*(DMID/64), 1,  272, 0};
  tp.d[3] = {W4,  W4t,  DMID, DMID, (DMID/64)*(DMID/64), 1,  528, 0};
  tp.d[4] = {BW1, BW1t, DMID, DMID, (DMID/64)*(DMID/64), NDOM, 784, 0};
  tp.d[5] = {BW2, BW2t, DMID, DMID, (DMID/64)*(DMID/64), NDOM, 1808, 0};
  tp.d[6] = {BW3, BW3t, DMID, DMID, (DMID/64)*(DMID/64), NDOM, 2832, 0};
  tp.d[7] = {BW4, BW4t, DMID, DOUT, (DMID/64)*(DOUT/64), NDOM, 3856, 0};
  tp.d[8] = {X,   Xh,   NROWS, DIN, (NROWS/64)*(DIN/64), 1,   3920, 2};
  transpose_cast_multi<<<3920 + 128, 256, 0, stream>>>(tp);

  setup_kernel<<<1, 1024, 0, stream>>>(domains, meta, sortpos, invperm);

  // layer 1 (K=64)
  gemm_f16<128, 1, true><<<dim3(DMID / 128, NROWS / 128), 256, 0, stream>>>(
      Xh, W1t, b1, bufA, DMID);

  // big K=1024 layers: dense grid 512 (64 row-tiles x 8 col), chunk 64
  gemm_mid<0, 0><<<512, 256, 0, stream>>>(bufA,  W2t, b2, bufS1, nullptr, nullptr, 64);
  gemm_mid<0, 0><<<512, 256, 0, stream>>>(bufS1, W3t, b3, bufA,  nullptr, nullptr, 64);
  gemm_mid<0, 1><<<512, 256, 0, stream>>>(bufA,  W4t, b4, bufS0, nullptr, sortpos, 64);
  // branch layers: grid 544 (68 x 8), chunk 68, 128-gran tile map
  gemm_mid<1, 0><<<544, 256, 0, stream>>>(bufS0, BW1t, Bb1, bufS1, meta2, nullptr, MAXT128);
  gemm_mid<1, 0><<<544, 256, 0, stream>>>(bufS1, BW2t, Bb2, bufS0, meta2, nullptr, MAXT128);
  gemm_mid<1, 0><<<544, 256, 0, stream>>>(bufS0, BW3t, Bb3, bufS1, meta2, nullptr, MAXT128);

  // final layer: split-K x4 partials, then reduce (+bias, +scatter)
  gemm_final<<<4 * MAXT128, 256, 0, stream>>>(bufS1, BW4t, meta2, Pbuf);
  reduce_final<<<MAXT128, 256, 0, stream>>>(Pbuf, Bb4, meta2, invperm, out);
}